// Round 1
// baseline (70.211 us; speedup 1.0000x reference)
//
#include <hip/hip_runtime.h>

// Output[g,i,j,:] = edge_dense[g,i,j,:] + emb_table[A[g,i,j]] * (A != 0)
//   A = 0 at edge positions (emb row 0 is zeros -> contribution 0)
//   A = 1 on the in-graph diagonal (i==j, i < counts[g])
//   A = 2 elsewhere
// Edges in this problem are unique and off-diagonal, so edge rows can
// overwrite the background emb value exactly.

__global__ void prep_kernel(const int* __restrict__ batch, int* __restrict__ ws,
                            int TN, int B) {
    // ws layout: [0,B) = exclusive offsets, [B,2B) = counts
    extern __shared__ int cnt[];
    for (int i = threadIdx.x; i < B; i += blockDim.x) cnt[i] = 0;
    __syncthreads();
    for (int v = threadIdx.x; v < TN; v += blockDim.x)
        atomicAdd(&cnt[batch[v]], 1);
    __syncthreads();
    if (threadIdx.x == 0) {
        int acc = 0;
        for (int g = 0; g < B; ++g) {
            int c = cnt[g];
            ws[g]     = acc;  // exclusive prefix (node offset of graph g)
            ws[B + g] = c;    // node count of graph g
            acc += c;
        }
    }
}

// One float4 per thread; block = (jPer columns) x (D4 float4 chunks),
// writes 256 threads * 16B = 4 KB contiguous per block.
__global__ void fill_kernel(float4* __restrict__ out, const float4* __restrict__ emb,
                            const int* __restrict__ counts, int N, int D4, int jPer) {
    int g  = blockIdx.z;
    int i  = blockIdx.y;
    int d4 = threadIdx.x % D4;
    int jj = threadIdx.x / D4;
    int j  = blockIdx.x * jPer + jj;
    if (j >= N) return;
    float4 v1 = emb[D4 + d4];        // emb_table[1]
    float4 v2 = emb[2 * D4 + d4];    // emb_table[2]
    bool diag = (j == i) && (i < counts[g]);
    float4 v = diag ? v1 : v2;
    size_t row = (size_t)(g * N + i);
    out[(row * N + j) * D4 + d4] = v;
}

// One float4 per thread over E*D4 units: coalesced read of edge_attr,
// 256B-row scatter into out.
__global__ void edge_kernel(const float4* __restrict__ attr, const int* __restrict__ eidx,
                            const int* __restrict__ batch, const int* __restrict__ offs,
                            float4* __restrict__ out, int E, int N, int D4) {
    int idx = blockIdx.x * blockDim.x + threadIdx.x;
    if (idx >= E * D4) return;
    int e  = idx / D4;
    int d4 = idx - e * D4;
    int s  = eidx[e];
    int d  = eidx[E + e];
    int g  = batch[s];
    int off = offs[g];
    int si = s - off;
    int di = d - off;
    float4 v = attr[(size_t)e * D4 + d4];
    out[(((size_t)g * N + si) * N + di) * D4 + d4] = v;
}

extern "C" void kernel_launch(void* const* d_in, const int* in_sizes, int n_in,
                              void* d_out, int out_size, void* d_ws, size_t ws_size,
                              hipStream_t stream) {
    const float* edge_attr  = (const float*)d_in[0];
    const float* emb_table  = (const float*)d_in[1];
    const int*   edge_index = (const int*)d_in[2];
    const int*   batch_vec  = (const int*)d_in[3];
    // d_in[4] = num_graphs, d_in[5] = max_nodes (device scalars; derive on host instead)

    int D  = in_sizes[1] / 3;                 // emb_table is [3, D]
    int E  = in_sizes[2] / 2;                 // edge_index is [2, E]
    int TN = in_sizes[3];                     // total nodes = B*N
    int D4 = D / 4;
    int N  = (int)((long long)out_size / ((long long)TN * (long long)D)); // B*N*N*D / (B*N*D)
    int B  = TN / N;

    float* out = (float*)d_out;
    int*   ws  = (int*)d_ws;                  // offs[0..B), counts[B..2B)

    prep_kernel<<<1, 1024, (size_t)B * sizeof(int), stream>>>(batch_vec, ws, TN, B);

    int jPer = 256 / D4;                      // columns per block (D4=16 -> 16)
    dim3 fgrid((N + jPer - 1) / jPer, N, B);
    fill_kernel<<<fgrid, 256, 0, stream>>>((float4*)out, (const float4*)emb_table,
                                           ws + B, N, D4, jPer);

    long long eunits = (long long)E * D4;
    int eblocks = (int)((eunits + 255) / 256);
    edge_kernel<<<eblocks, 256, 0, stream>>>((const float4*)edge_attr, edge_index,
                                             batch_vec, ws, (float4*)out, E, N, D4);
}